// Round 3
// baseline (51.475 us; speedup 1.0000x reference)
//
#include <hip/hip_runtime.h>

#define YDIM 30
#define PLANE4 16384            // 256*256/4 float4 per y-plane
#define NTHR 256
#define NBLK 512                // 512*256 threads * 4 px = 524288 pixels
#define NPIX 15728640.0         // 8*30*65536

__global__ __launch_bounds__(NTHR) void drl_fused(const float4* __restrict__ out,
                                                  unsigned int* __restrict__ cnt,
                                                  float* __restrict__ partial,
                                                  float* __restrict__ lossp) {
    const int g = blockIdx.x * NTHR + threadIdx.x;     // float4-group id
    const int b = g >> 14;                             // batch
    const int hw4 = g & 16383;

    const float4* p0 = out + (size_t)b * (2 * YDIM * PLANE4) + hw4;  // out[b][0]
    const float4* p1 = p0 + YDIM * PLANE4;                            // out[b][1]

    // running moments of out0 and out1, with snapshots at the argmin update
    float run_s[4]={0,0,0,0}, run_sx[4]={0,0,0,0};          // Σc0, Σy·c0
    float s1[4]={0,0,0,0}, s1x[4]={0,0,0,0}, s1q[4]={0,0,0,0}; // Σt1, Σy·t1, Σt1²
    float sn_s[4]={0,0,0,0}, sn_sx[4]={0,0,0,0};            // prefix snapshots (j<d)
    float sn_s1[4]={0,0,0,0}, sn_s1x[4]={0,0,0,0};
    float best[4]={-7,-7,-7,-7};                            // diff[0] = -DIST_IND
    float fd[4]={0,0,0,0};
    float prev[4];

#pragma unroll
    for (int y = 0; y < YDIM; ++y) {
        float4 v0 = p0[y * PLANE4];
        float4 v1 = p1[y * PLANE4];
        float c0[4] = {v0.x, v0.y, v0.z, v0.w};
        float t1[4] = {v1.x, v1.y, v1.z, v1.w};
        if (y >= 2 && y <= YDIM - 2) {      // diff[1], diff[29] forced to 0 in ref
#pragma unroll
            for (int c = 0; c < 4; ++c) {
                float df = c0[c] - prev[c];
                bool lt = df < best[c];     // strict < = first-occurrence argmin
                best[c]  = lt ? df        : best[c];
                fd[c]    = lt ? (float)y  : fd[c];
                sn_s[c]  = lt ? run_s[c]  : sn_s[c];
                sn_sx[c] = lt ? run_sx[c] : sn_sx[c];
                sn_s1[c] = lt ? s1[c]     : sn_s1[c];
                sn_s1x[c]= lt ? s1x[c]    : sn_s1x[c];
            }
        }
#pragma unroll
        for (int c = 0; c < 4; ++c) {
            run_s[c] += c0[c];
            run_sx[c] = fmaf((float)y, c0[c], run_sx[c]);
            s1[c]    += t1[c];
            s1x[c]    = fmaf((float)y, t1[c], s1x[c]);
            s1q[c]    = fmaf(t1[c], t1[c], s1q[c]);
            prev[c]   = c0[c];
        }
    }

    float accT = 0.f;
#pragma unroll
    for (int c = 0; c < 4; ++c) {
        float d   = fd[c];
        float nb  = d;
        float na  = (float)YDIM - d;        // >= 2 always (d <= 28)
        float nsb = fmaxf(nb, 1.f);
        // data sums per segment (segment-a uses x' = y - d)
        float Syb  = sn_s[c];
        float Sxyb = sn_sx[c];
        float Sya  = run_s[c] - sn_s[c];
        float Sxya = fmaf(-d, Sya, run_sx[c] - sn_sx[c]);
        // fit (reference quirks: raw slope in intercept, clipped slope in fitted)
        float mxb = nb * (nb - 1.f) * 0.5f / nsb;
        float myb = Syb / nsb;
        float mxa = (na - 1.f) * 0.5f;
        float mya = Sya / na;
        float covb = fmaf(-mxb, Syb, Sxyb);
        float cova = fmaf(-mxa, Sya, Sxya);
        float varb = nb * (nb * nb - 1.f) * (1.f / 12.f);
        float vara = na * (na * na - 1.f) * (1.f / 12.f);
        float slb = (varb > 0.f) ? covb / fmaxf(varb, 1.f) : 0.f;
        float sla = (vara > 0.f) ? cova / fmaxf(vara, 1.f) : 0.f;
        float ib = fminf(fmaxf(myb - slb * mxb, 0.f), 100.f);
        float ia = fminf(fmaxf(mya - sla * mxa, 0.f), 100.f);
        float qb = fminf(fmaxf(slb, 0.f), 2.f);
        float qa = fminf(fmaxf(sla, 0.f), 2.f);
        // closed-form sum of (fit - t1)^2 over y
        float Sy_b  = nb * (nb - 1.f) * 0.5f;
        float Syy_b = nb * (nb - 1.f) * (2.f * nb - 1.f) * (1.f / 6.f);
        float Sx_a  = na * (na - 1.f) * 0.5f;
        float Sxx_a = na * (na - 1.f) * (2.f * na - 1.f) * (1.f / 6.f);
        float T1b  = sn_s1[c];
        float T1yb = sn_s1x[c];
        float T1a  = s1[c] - sn_s1[c];
        float T1xa = fmaf(-d, T1a, s1x[c] - sn_s1x[c]);
        float Lb = qb * qb * Syy_b + 2.f * qb * ib * Sy_b + nb * ib * ib
                 - 2.f * fmaf(qb, T1yb, ib * T1b);
        float La = qa * qa * Sxx_a + 2.f * qa * ia * Sx_a + na * ia * ia
                 - 2.f * fmaf(qa, T1xa, ia * T1a);
        accT += Lb + La + s1q[c];
    }

    // wave (64) reduce, then cross-wave via LDS
#pragma unroll
    for (int off = 32; off > 0; off >>= 1) accT += __shfl_down(accT, off, 64);
    __shared__ float wsum[NTHR / 64];
    __shared__ bool last;
    if ((threadIdx.x & 63) == 0) wsum[threadIdx.x >> 6] = accT;
    __syncthreads();
    if (threadIdx.x == 0) {
        float bs = (wsum[0] + wsum[1]) + (wsum[2] + wsum[3]);
        __hip_atomic_store(&partial[blockIdx.x], bs, __ATOMIC_RELEASE,
                           __HIP_MEMORY_SCOPE_AGENT);
        unsigned int old = __hip_atomic_fetch_add(cnt, 1u, __ATOMIC_ACQ_REL,
                                                  __HIP_MEMORY_SCOPE_AGENT);
        last = (old == NBLK - 1);
    }
    __syncthreads();

    if (last) {  // block-uniform: final deterministic reduction by the last block
        double s = 0.0;
        for (int i = threadIdx.x; i < NBLK; i += NTHR)
            s += (double)__hip_atomic_load(&partial[i], __ATOMIC_ACQUIRE,
                                           __HIP_MEMORY_SCOPE_AGENT);
        __shared__ double sm[NTHR];
        sm[threadIdx.x] = s;
        __syncthreads();
        for (int st = NTHR / 2; st > 0; st >>= 1) {
            if (threadIdx.x < st) sm[threadIdx.x] += sm[threadIdx.x + st];
            __syncthreads();
        }
        if (threadIdx.x == 0) lossp[0] = (float)(sm[0] / NPIX);
    }
}

extern "C" void kernel_launch(void* const* d_in, const int* in_sizes, int n_in,
                              void* d_out, int out_size, void* d_ws, size_t ws_size,
                              hipStream_t stream) {
    const float4* out_t = (const float4*)d_in[0];   // (8,2,30,256,256) f32
    // d_in[1] = target: unused by the reference loss
    unsigned int* cnt = (unsigned int*)d_ws;        // [0]: arrival counter
    float* partial = (float*)((char*)d_ws + 128);   // NBLK block partials
    float* loss    = (float*)d_out;

    hipMemsetAsync(d_ws, 0, 4, stream);             // zero the counter (capturable)
    drl_fused<<<NBLK, NTHR, 0, stream>>>(out_t, cnt, partial, loss);
}